// Round 1
// baseline (296.475 us; speedup 1.0000x reference)
//
#include <hip/hip_runtime.h>
#include <stdint.h>

// Problem constants
// LATENT=128, HIDDEN=2048, N_PARTS=128, K=2048
// omega: (1152,2048), transf: (1536,2048), rotations: (1152,2048), translations: (384,2048)

typedef short bf16x8 __attribute__((ext_vector_type(8)));
typedef float f32x4 __attribute__((ext_vector_type(4)));

__device__ __forceinline__ unsigned short f2bf(float f) {
  unsigned int x = __float_as_uint(f);
  unsigned int r = (x + 0x7fffu + ((x >> 16) & 1u)) >> 16;
  return (unsigned short)r;
}

__device__ __forceinline__ void gld_lds16(const void* g, void* l) {
  __builtin_amdgcn_global_load_lds(
      (__attribute__((address_space(1))) void*)(g),
      (__attribute__((address_space(3))) void*)(l),
      16, 0, 0);
}

// ---------------------------------------------------------------------------
// Weight fp32 -> bf16 cast, all 8 weights in one grid-stride-free pass.
// Segment layout in dst (elements):
//  wo0 [0,262144) wo1 [262144,4456448) wo2 [4456448,8650752) wo3 [8650752,11010048)
//  wt0 [11010048,11272192) wt1 [11272192,15466496) wt2 [15466496,19660800) wt3 [19660800,20447232)
__global__ void cast_weights_k(const float* __restrict__ wo0, const float* __restrict__ wo1,
                               const float* __restrict__ wo2, const float* __restrict__ wo3,
                               const float* __restrict__ wt0, const float* __restrict__ wt1,
                               const float* __restrict__ wt2, const float* __restrict__ wt3,
                               unsigned short* __restrict__ dst) {
  int gid = blockIdx.x * 256 + threadIdx.x;
  int idx = gid * 4;
  if (idx >= 20447232) return;
  const float* src;
  int off;
  if (idx < 8650752) {
    if (idx < 262144)       { src = wo0; off = idx; }
    else if (idx < 4456448) { src = wo1; off = idx - 262144; }
    else                    { src = wo2; off = idx - 4456448; }
  } else {
    if (idx < 11010048)      { src = wo3; off = idx - 8650752; }
    else if (idx < 11272192) { src = wt0; off = idx - 11010048; }
    else if (idx < 15466496) { src = wt1; off = idx - 11272192; }
    else if (idx < 19660800) { src = wt2; off = idx - 15466496; }
    else                     { src = wt3; off = idx - 19660800; }
  }
  float4 v = *(const float4*)(src + off);
  ushort4 o;
  o.x = f2bf(v.x); o.y = f2bf(v.y); o.z = f2bf(v.z); o.w = f2bf(v.w);
  *(ushort4*)(dst + idx) = o;
}

// ---------------------------------------------------------------------------
// x (128 x 2048) fp32 -> Xt (2048 x 128) bf16 via LDS tile transpose
__global__ void transpose_cast_k(const float* __restrict__ x, unsigned short* __restrict__ xt) {
  __shared__ float tile[32][33];
  const int bx = blockIdx.x;  // 64 tiles over K=2048
  const int by = blockIdx.y;  // 4 tiles over LATENT=128
  const int tx = threadIdx.x; // 32
  const int ty = threadIdx.y; // 8
#pragma unroll
  for (int i = 0; i < 32; i += 8)
    tile[ty + i][tx] = x[(size_t)(by * 32 + ty + i) * 2048 + bx * 32 + tx];
  __syncthreads();
#pragma unroll
  for (int i = 0; i < 32; i += 8)
    xt[(size_t)(bx * 32 + ty + i) * 128 + by * 32 + tx] = f2bf(tile[tx][ty + i]);
}

// ---------------------------------------------------------------------------
// TN GEMM: C(M x N) = A(M x K) * B(N x K)^T, bf16 in, fp32 acc.
// Two independent problems fused via blockIdx.y (same M, same K).
// MODE 0: relu + bf16 out.  MODE 1: fp32 out, no relu.
// Tile 128x128, BK=32, block = 256 threads (4 waves, 2x2 of 64x64 per wave).
template <int MODE>
__global__ __launch_bounds__(256, 2) void gemm_tn(
    const unsigned short* __restrict__ A0, const unsigned short* __restrict__ B0,
    void* __restrict__ C0v, int n0tiles, int ldc0,
    const unsigned short* __restrict__ A1, const unsigned short* __restrict__ B1,
    void* __restrict__ C1v, int ldc1, int K) {
  __shared__ unsigned short Asl[128 * 32];
  __shared__ unsigned short Bsl[128 * 32];

  int yt = blockIdx.y;
  const unsigned short* A;
  const unsigned short* B;
  char* C;
  int ldc;
  if (yt < n0tiles) { A = A0; B = B0; C = (char*)C0v; ldc = ldc0; }
  else { A = A1; B = B1; C = (char*)C1v; ldc = ldc1; yt -= n0tiles; }

  const int mt = blockIdx.x;
  const unsigned short* Ab = A + (size_t)mt * 128 * K;
  const unsigned short* Bb = B + (size_t)yt * 128 * K;

  const int tid = threadIdx.x;
  const int wave = tid >> 6, lane = tid & 63;
  const int mw = (wave >> 1) * 64, nw = (wave & 1) * 64;
  const int l16 = lane & 15, quad = lane >> 4;

  f32x4 acc[4][4] = {};

  for (int k0 = 0; k0 < K; k0 += 32) {
    // Stage A/B 128x32 bf16 tiles (8 KB each) via async global->LDS, 16B/lane.
    // chunk c: row = c>>2, seg = c&3; LDS dest = base + c*16 (lane-contiguous).
#pragma unroll
    for (int i = 0; i < 2; ++i) {
      int c = i * 256 + tid;
      int row = c >> 2, seg = c & 3;
      gld_lds16(Ab + (size_t)row * K + k0 + seg * 8, &Asl[c * 8]);
      gld_lds16(Bb + (size_t)row * K + k0 + seg * 8, &Bsl[c * 8]);
    }
    __syncthreads();

    bf16x8 af[4], bfr[4];
#pragma unroll
    for (int t = 0; t < 4; ++t) {
      af[t]  = *(const bf16x8*)&Asl[(mw + t * 16 + l16) * 32 + quad * 8];
      bfr[t] = *(const bf16x8*)&Bsl[(nw + t * 16 + l16) * 32 + quad * 8];
    }
#pragma unroll
    for (int tm = 0; tm < 4; ++tm)
#pragma unroll
      for (int tn = 0; tn < 4; ++tn)
        acc[tm][tn] = __builtin_amdgcn_mfma_f32_16x16x32_bf16(af[tm], bfr[tn], acc[tm][tn], 0, 0, 0);
    __syncthreads();
  }

  // Epilogue: C/D layout col=lane&15, row=quad*4+reg (m89-verified).
  const int mbase = mt * 128 + mw;
  const int nbase = yt * 128 + nw;
#pragma unroll
  for (int tm = 0; tm < 4; ++tm) {
#pragma unroll
    for (int tn = 0; tn < 4; ++tn) {
      int col = nbase + tn * 16 + l16;
      int row0 = mbase + tm * 16 + quad * 4;
#pragma unroll
      for (int r = 0; r < 4; ++r) {
        float v = acc[tm][tn][r];
        if (MODE == 0) {
          v = fmaxf(v, 0.0f);
          ((unsigned short*)C)[(size_t)(row0 + r) * ldc + col] = f2bf(v);
        } else {
          ((float*)C)[(size_t)(row0 + r) * ldc + col] = v;
        }
      }
    }
  }
}

// ---------------------------------------------------------------------------
// expm(3x3) + output assembly.
__device__ __forceinline__ void mm3(const float* a, const float* b, float* c) {
#pragma unroll
  for (int r = 0; r < 3; ++r)
#pragma unroll
    for (int cc = 0; cc < 3; ++cc)
      c[r * 3 + cc] = a[r * 3 + 0] * b[0 + cc] + a[r * 3 + 1] * b[3 + cc] + a[r * 3 + 2] * b[6 + cc];
}

__global__ void finalize_k(const float* __restrict__ omega_t, const float* __restrict__ trans_t,
                           float* __restrict__ out) {
  const int k = blockIdx.x * 256 + threadIdx.x;  // column index, 0..2047
  const int j = blockIdx.y;                      // part index, 0..127

  float a[9];
#pragma unroll
  for (int i = 0; i < 9; ++i) a[i] = omega_t[(size_t)k * 1152 + 9 * j + i];

  float* omega  = out;
  float* transf = out + (size_t)1152 * 2048;
  float* rot    = out + (size_t)(1152 + 1536) * 2048;
  float* transl = out + (size_t)(1152 + 1536 + 1152) * 2048;

#pragma unroll
  for (int i = 0; i < 9; ++i) omega[(size_t)(9 * j + i) * 2048 + k] = a[i];

  // expm via scaling-and-squaring + order-12 Taylor (scaled ||A||_1 <= 0.25)
  float n1 = 0.f;
#pragma unroll
  for (int c = 0; c < 3; ++c) {
    float s = fabsf(a[c]) + fabsf(a[3 + c]) + fabsf(a[6 + c]);
    n1 = fmaxf(n1, s);
  }
  int s = 0;
  if (n1 > 0.25f) {
    s = (int)ceilf(log2f(n1 * 4.0f));
    if (s < 0) s = 0;
  }
  const float scl = exp2f((float)(-s));
  float As[9];
#pragma unroll
  for (int i = 0; i < 9; ++i) As[i] = a[i] * scl;

  float E[9] = {1, 0, 0, 0, 1, 0, 0, 0, 1};
  float T[9] = {1, 0, 0, 0, 1, 0, 0, 0, 1};
#pragma unroll
  for (int t = 1; t <= 12; ++t) {
    float Tn[9];
    mm3(T, As, Tn);
    const float inv = 1.0f / (float)t;
#pragma unroll
    for (int i = 0; i < 9; ++i) { T[i] = Tn[i] * inv; E[i] += T[i]; }
  }
  for (int q = 0; q < s; ++q) {
    float Tn[9];
    mm3(E, E, Tn);
#pragma unroll
    for (int i = 0; i < 9; ++i) E[i] = Tn[i];
  }

#pragma unroll
  for (int i = 0; i < 9; ++i) {
    rot[(size_t)(9 * j + i) * 2048 + k] = E[i];
    transf[(size_t)(12 * j + i) * 2048 + k] = E[i];
  }
  float tr[3];
#pragma unroll
  for (int c = 0; c < 3; ++c) tr[c] = trans_t[(size_t)k * 384 + 3 * j + c];
#pragma unroll
  for (int c = 0; c < 3; ++c) {
    transf[(size_t)(12 * j + 9 + c) * 2048 + k] = tr[c];
    transl[(size_t)(3 * j + c) * 2048 + k] = tr[c];
  }
}

// ---------------------------------------------------------------------------
extern "C" void kernel_launch(void* const* d_in, const int* in_sizes, int n_in,
                              void* d_out, int out_size, void* d_ws, size_t ws_size,
                              hipStream_t stream) {
  const float* x   = (const float*)d_in[0];
  const float* Wo0 = (const float*)d_in[1];
  const float* Wo1 = (const float*)d_in[2];
  const float* Wo2 = (const float*)d_in[3];
  const float* Wo3 = (const float*)d_in[4];
  const float* Wt0 = (const float*)d_in[5];
  const float* Wt1 = (const float*)d_in[6];
  const float* Wt2 = (const float*)d_in[7];
  const float* Wt3 = (const float*)d_in[8];

  // Workspace carve (elements): 20,447,232 bf16 weights; Xt; 4 H buffers; fp32 finals
  unsigned short* wb   = (unsigned short*)d_ws;
  unsigned short* wo0b = wb + 0;
  unsigned short* wo1b = wb + 262144;
  unsigned short* wo2b = wb + 4456448;
  unsigned short* wo3b = wb + 8650752;
  unsigned short* wt0b = wb + 11010048;
  unsigned short* wt1b = wb + 11272192;
  unsigned short* wt2b = wb + 15466496;
  unsigned short* wt3b = wb + 19660800;
  unsigned short* Xt   = wb + 20447232;  // 2048 x 128
  unsigned short* HoA  = Xt + 262144;    // 2048 x 2048 each
  unsigned short* HoB  = HoA + 4194304;
  unsigned short* HtA  = HoB + 4194304;
  unsigned short* HtB  = HtA + 4194304;
  float* omega_t = (float*)(HtB + 4194304);  // 2048 x 1152 fp32
  float* trans_t = omega_t + 2359296;        // 2048 x 384 fp32
  // total ws use ~87.6 MB

  cast_weights_k<<<19968, 256, 0, stream>>>(Wo0, Wo1, Wo2, Wo3, Wt0, Wt1, Wt2, Wt3, wb);
  transpose_cast_k<<<dim3(64, 4), dim3(32, 8), 0, stream>>>(x, Xt);

  // L0: K=128, both chains from Xt
  gemm_tn<0><<<dim3(16, 32), 256, 0, stream>>>(Xt, wo0b, HoA, 16, 2048, Xt, wt0b, HtA, 2048, 128);
  // L1: K=2048
  gemm_tn<0><<<dim3(16, 32), 256, 0, stream>>>(HoA, wo1b, HoB, 16, 2048, HtA, wt1b, HtB, 2048, 2048);
  // L2: K=2048
  gemm_tn<0><<<dim3(16, 32), 256, 0, stream>>>(HoB, wo2b, HoA, 16, 2048, HtB, wt2b, HtA, 2048, 2048);
  // L3: omega (N=1152) + translations (N=384), fp32 out
  gemm_tn<1><<<dim3(16, 12), 256, 0, stream>>>(HoA, wo3b, omega_t, 9, 1152, HtA, wt3b, trans_t, 384, 2048);

  finalize_k<<<dim3(8, 128), 256, 0, stream>>>(omega_t, trans_t, (float*)d_out);
}